// Round 2
// baseline (30.118 us; speedup 1.0000x reference)
//
#include <hip/hip_runtime.h>
#include <hip/hip_fp16.h>

#define NCTX   512
#define NHEADS 8
#define WIDTH  64
#define TI     32   // k rows per block
#define TJ     64   // q rows per block
#define PAD    72   // f16 row stride: 144 B, 16-B aligned, 36 dwords -> conflict-free

typedef _Float16 h2 __attribute__((ext_vector_type(2)));
typedef _Float16 h4 __attribute__((ext_vector_type(4)));
typedef _Float16 h8 __attribute__((ext_vector_type(8)));

#define QROWS (NHEADS * TJ)   // 512
#define KROWS (NHEADS * TI)   // 256
#define LDS_BYTES ((QROWS + KROWS) * PAD * 2)   // 110592 B

__global__ __launch_bounds__(512, 2)
void l1attn_kernel(const float* __restrict__ qg, const float* __restrict__ kg,
                   float* __restrict__ out) {
    extern __shared__ __align__(16) _Float16 smem[];
    _Float16* qs = smem;               // [NHEADS][TJ][PAD]
    _Float16* ks = smem + QROWS * PAD; // [NHEADS][TI][PAD]

    const int t  = threadIdx.x;
    const int b  = blockIdx.z;
    const int i0 = blockIdx.y * TI;
    const int j0 = blockIdx.x * TJ;

    // ---- stage Q tile: q[b, j0..j0+63, :, :] is one contiguous 128 KB span ----
    {
        const float4* src = (const float4*)(qg + ((size_t)b * NCTX + j0) * NHEADS * WIDTH);
        #pragma unroll
        for (int r = 0; r < (TJ * NHEADS * WIDTH / 4) / 512; ++r) {
            int f = t + r * 512;
            float4 v = src[f];
            int j  = f >> 7;        // /128  (16 float4 per (j,h) row, 8 h)
            int h  = (f >> 4) & 7;
            int w4 = f & 15;
            h2 lo = __builtin_bit_cast(h2, __builtin_amdgcn_cvt_pkrtz(v.x, v.y));
            h2 hi = __builtin_bit_cast(h2, __builtin_amdgcn_cvt_pkrtz(v.z, v.w));
            h4 pk = {lo.x, lo.y, hi.x, hi.y};
            *(h4*)(qs + (h * TJ + j) * PAD + w4 * 4) = pk;
        }
    }
    // ---- stage K tile: k[b, i0..i0+31, :, :] contiguous 64 KB span ----
    {
        const float4* src = (const float4*)(kg + ((size_t)b * NCTX + i0) * NHEADS * WIDTH);
        #pragma unroll
        for (int r = 0; r < (TI * NHEADS * WIDTH / 4) / 512; ++r) {
            int f = t + r * 512;
            float4 v = src[f];
            int i  = f >> 7;
            int h  = (f >> 4) & 7;
            int w4 = f & 15;
            h2 lo = __builtin_bit_cast(h2, __builtin_amdgcn_cvt_pkrtz(v.x, v.y));
            h2 hi = __builtin_bit_cast(h2, __builtin_amdgcn_cvt_pkrtz(v.z, v.w));
            h4 pk = {lo.x, lo.y, hi.x, hi.y};
            *(h4*)(ks + (h * TI + i) * PAD + w4 * 4) = pk;
        }
    }
    __syncthreads();

    // ---- compute: wave w owns head h = w; 64 lanes = 8 tx (j) x 8 ty (i) ----
    const int h    = t >> 6;
    const int lane = t & 63;
    const int tx   = lane & 7;   // j sub-index
    const int ty   = lane >> 3;  // i sub-index

    const _Float16* qh = qs + (h * TJ) * PAD;
    const _Float16* kh = ks + (h * TI) * PAD;

    float acc[8][4];
    #pragma unroll
    for (int m = 0; m < 8; ++m)
        #pragma unroll
        for (int n = 0; n < 4; ++n) acc[m][n] = 0.f;

    const h2 one2 = {(_Float16)1.f, (_Float16)1.f};

    #pragma unroll
    for (int w8 = 0; w8 < WIDTH / 8; ++w8) {
        h8 qv[8];
        h8 kv[4];
        #pragma unroll
        for (int m = 0; m < 8; ++m)
            qv[m] = *(const h8*)(qh + (tx + 8 * m) * PAD + 8 * w8);
        #pragma unroll
        for (int n = 0; n < 4; ++n)
            kv[n] = *(const h8*)(kh + (ty + 8 * n) * PAD + 8 * w8);
        #pragma unroll
        for (int m = 0; m < 8; ++m)
            #pragma unroll
            for (int n = 0; n < 4; ++n)
                #pragma unroll
                for (int p = 0; p < 4; ++p) {
                    h2 a = { qv[m][2 * p], qv[m][2 * p + 1] };
                    h2 c = { kv[n][2 * p], kv[n][2 * p + 1] };
                    h2 d = a - c;                                   // v_pk_add_f16 (neg)
                    unsigned ud = __builtin_bit_cast(unsigned, d) & 0x7fff7fffu;  // |.|
                    d = __builtin_bit_cast(h2, ud);
                    acc[m][n] = __builtin_amdgcn_fdot2(d, one2, acc[m][n], false);
                }
    }

    // ---- write: out[b][i][j][h], i = k-row index, j = q-row index ----
    const float s = -0.125f;  // -1/sqrt(64)
    #pragma unroll
    for (int n = 0; n < 4; ++n) {
        int i = i0 + ty + 8 * n;
        size_t rowbase = (((size_t)b * NCTX + i) * NCTX + j0) * NHEADS + h;
        #pragma unroll
        for (int m = 0; m < 8; ++m) {
            out[rowbase + (size_t)(tx + 8 * m) * NHEADS] = acc[m][n] * s;
        }
    }
}

extern "C" void kernel_launch(void* const* d_in, const int* in_sizes, int n_in,
                              void* d_out, int out_size, void* d_ws, size_t ws_size,
                              hipStream_t stream) {
    const float* q = (const float*)d_in[0];
    const float* k = (const float*)d_in[1];
    float* out = (float*)d_out;

    (void)hipFuncSetAttribute(reinterpret_cast<const void*>(l1attn_kernel),
                              hipFuncAttributeMaxDynamicSharedMemorySize, LDS_BYTES);

    dim3 grid(NCTX / TJ, NCTX / TI, 2);   // (j tiles, i tiles, batch) = 8 x 16 x 2
    l1attn_kernel<<<grid, 512, LDS_BYTES, stream>>>(q, k, out);
}

// Round 3
// 21.844 us; speedup vs baseline: 1.3788x; 1.3788x over previous
//
#include <hip/hip_runtime.h>

typedef _Float16 h2 __attribute__((ext_vector_type(2)));
typedef _Float16 h4 __attribute__((ext_vector_type(4)));
typedef _Float16 h8 __attribute__((ext_vector_type(8)));

#define NCTX   512
#define NHEADS 8
#define WIDTH  64
#define TI     32
#define TJ     32
#define PAD    72          // halves; row stride 144 B = 36 dwords -> 8 consecutive rows tile all 32 banks
#define ROWS   256         // 32 rows x 8 heads
#define LDS_BYTES (2 * ROWS * PAD * 2)   // 73728

__global__ __launch_bounds__(512, 4)
void l1attn_kernel(const float* __restrict__ qg, const float* __restrict__ kg,
                   float* __restrict__ out) {
    extern __shared__ __align__(16) _Float16 smem[];
    _Float16* qs = smem;              // [256 rows = j*8+h][PAD]
    _Float16* ks = smem + ROWS * PAD; // [256 rows = i*8+h][PAD]

    const int t = threadIdx.x;

    // XCD-aware decode: all blocks sharing a j-tile (same q slice) land on one XCD.
    const int bid  = blockIdx.x;        // 0..511
    const int xcd  = bid & 7;
    const int slot = bid >> 3;          // 0..63
    const int jt   = xcd * 2 + (slot >> 5);
    const int it   = slot & 15;
    const int b    = (slot >> 4) & 1;
    const int i0   = it * TI;
    const int j0   = jt * TJ;

    // ---- stage Q tile: 32 j-rows x 8 h x 64 w fp32 (contiguous 64 KB) -> f16 LDS ----
    {
        const float4* src = (const float4*)(qg + ((size_t)b * NCTX + j0) * (NHEADS * WIDTH));
        #pragma unroll
        for (int rr = 0; rr < 8; ++rr) {
            int f = t + rr * 512;                 // 0..4095 float4s
            float4 v = src[f];
            h2 lo = __builtin_bit_cast(h2, __builtin_amdgcn_cvt_pkrtz(v.x, v.y));
            h2 hi = __builtin_bit_cast(h2, __builtin_amdgcn_cvt_pkrtz(v.z, v.w));
            h4 pk = {lo.x, lo.y, hi.x, hi.y};
            *(h4*)(qs + (f >> 4) * PAD + (f & 15) * 4) = pk;   // row = j*8+h = f>>4
        }
    }
    // ---- stage K tile: 32 i-rows x 8 h x 64 w fp32 -> f16 LDS ----
    {
        const float4* src = (const float4*)(kg + ((size_t)b * NCTX + i0) * (NHEADS * WIDTH));
        #pragma unroll
        for (int rr = 0; rr < 8; ++rr) {
            int f = t + rr * 512;
            float4 v = src[f];
            h2 lo = __builtin_bit_cast(h2, __builtin_amdgcn_cvt_pkrtz(v.x, v.y));
            h2 hi = __builtin_bit_cast(h2, __builtin_amdgcn_cvt_pkrtz(v.z, v.w));
            h4 pk = {lo.x, lo.y, hi.x, hi.y};
            *(h4*)(ks + (f >> 4) * PAD + (f & 15) * 4) = pk;   // row = i*8+h
        }
    }
    __syncthreads();

    // ---- compute: wave w -> i = i0 + w + 8n; lane l: h = l&7, j = j0 + (l>>3) + 8m ----
    const int w = t >> 6;
    const int l = t & 63;
    const int h = l & 7;

    float acc[4][4];
    #pragma unroll
    for (int m = 0; m < 4; ++m)
        #pragma unroll
        for (int n = 0; n < 4; ++n) acc[m][n] = 0.f;

    const h2 one2 = {(_Float16)1.f, (_Float16)1.f};

    #pragma unroll
    for (int w8 = 0; w8 < WIDTH / 8; ++w8) {
        h8 qv[4], kv[4];
        #pragma unroll
        for (int m = 0; m < 4; ++m)     // q row = l + 64m  (64 distinct, bank-tiled)
            qv[m] = *(const h8*)(qs + (l + 64 * m) * PAD + 8 * w8);
        #pragma unroll
        for (int n = 0; n < 4; ++n)     // k row = 8w + 64n + h (8 distinct, 8-way broadcast)
            kv[n] = *(const h8*)(ks + (8 * w + 64 * n + h) * PAD + 8 * w8);
        #pragma unroll
        for (int m = 0; m < 4; ++m)
            #pragma unroll
            for (int n = 0; n < 4; ++n)
                #pragma unroll
                for (int p = 0; p < 4; ++p) {
                    h2 a = { qv[m][2 * p], qv[m][2 * p + 1] };
                    h2 c = { kv[n][2 * p], kv[n][2 * p + 1] };
                    h2 d = a - c;                                  // v_pk_add_f16 (neg)
                    unsigned ud = __builtin_bit_cast(unsigned, d) & 0x7fff7fffu;
                    d = __builtin_bit_cast(h2, ud);
                    acc[m][n] = __builtin_amdgcn_fdot2(d, one2, acc[m][n], false);
                }
    }

    // ---- coalesced write: per (m,n) store, 64 lanes = 64 consecutive dwords ----
    const float s = -0.125f;
    #pragma unroll
    for (int n = 0; n < 4; ++n) {
        size_t base = (((size_t)b * NCTX + (i0 + w + 8 * n)) * NCTX + j0) * NHEADS;
        #pragma unroll
        for (int m = 0; m < 4; ++m)
            out[base + 64 * m + l] = acc[m][n] * s;
    }
}

extern "C" void kernel_launch(void* const* d_in, const int* in_sizes, int n_in,
                              void* d_out, int out_size, void* d_ws, size_t ws_size,
                              hipStream_t stream) {
    const float* q = (const float*)d_in[0];
    const float* k = (const float*)d_in[1];
    float* out = (float*)d_out;

    (void)hipFuncSetAttribute(reinterpret_cast<const void*>(l1attn_kernel),
                              hipFuncAttributeMaxDynamicSharedMemorySize, LDS_BYTES);

    l1attn_kernel<<<dim3(512), dim3(512), LDS_BYTES, stream>>>(q, k, out);
}